// Round 1
// 1232.237 us; speedup vs baseline: 1.8329x; 1.8329x over previous
//
#include <hip/hip_runtime.h>

// Sinkhorn: B=256 batches, N=512, 50 iterations, REG=1.
//   k_makeK:    K = bf16(exp(-cost)) into the first 128 MB of d_out.
//   k_sinkhorn: one 1024-thread block per batch. FUSED sweeps: per K row,
//               compute row-dot with v (-> u_i) AND accumulate u_i*K_i into
//               next-iteration column sums. 51 K passes instead of 100.
//               First 112 rows of each batch's K stashed in LDS (112 KB).
//   k_out:      out[b,i,j] = log u[b,i] - cost[b,i,j] + log v[b,j].

#define SK_B   256
#define SK_N   512
#define SK_NIT 50
#define SK_LR  112   // K rows resident in LDS (of 512); 112*64*16B = 112 KB

__device__ __forceinline__ unsigned short f2bf_rne(float f) {
    union { float f; unsigned int u; } x; x.f = f;
    unsigned int r = (x.u + 0x7FFFu + ((x.u >> 16) & 1u)) >> 16;
    return (unsigned short)r;
}
__device__ __forceinline__ float bf_lo(unsigned int u) {
    union { unsigned int u; float f; } x; x.u = u << 16; return x.f;
}
__device__ __forceinline__ float bf_hi(unsigned int u) {
    union { unsigned int u; float f; } x; x.u = u & 0xffff0000u; return x.f;
}

__global__ void k_makeK(const float4* __restrict__ cost, ushort4* __restrict__ K, int n4) {
    int stride = gridDim.x * blockDim.x;
    for (int i = blockIdx.x * blockDim.x + threadIdx.x; i < n4; i += stride) {
        float4 c = cost[i];
        ushort4 o;
        o.x = f2bf_rne(__expf(-c.x));
        o.y = f2bf_rne(__expf(-c.y));
        o.z = f2bf_rne(__expf(-c.z));
        o.w = f2bf_rne(__expf(-c.w));
        K[i] = o;
    }
}

// unpack 8 bf16 cols of one row segment (cols lane*8 .. lane*8+7)
#define SK_UNPACK(p) \
    const float k0 = bf_lo((p).x), k1 = bf_hi((p).x), k2 = bf_lo((p).y), k3 = bf_hi((p).y), \
                k4 = bf_lo((p).z), k5 = bf_hi((p).z), k6 = bf_lo((p).w), k7 = bf_hi((p).w)

// row dot with v (two partial chains) + 64-lane butterfly reduce -> sv in ALL lanes
#define SK_DOT_RED(sv) \
    float sv; { \
        float s0_ = k0 * vv0; s0_ = fmaf(k2, vv2, s0_); s0_ = fmaf(k4, vv4, s0_); s0_ = fmaf(k6, vv6, s0_); \
        float s1_ = k1 * vv1; s1_ = fmaf(k3, vv3, s1_); s1_ = fmaf(k5, vv5, s1_); s1_ = fmaf(k7, vv7, s1_); \
        sv = s0_ + s1_; \
        sv += __shfl_xor(sv, 32, 64); sv += __shfl_xor(sv, 16, 64); sv += __shfl_xor(sv, 8, 64); \
        sv += __shfl_xor(sv, 4, 64);  sv += __shfl_xor(sv, 2, 64);  sv += __shfl_xor(sv, 1, 64); \
    }

#define SK_LOADVV() \
    const float vv0 = v_s[lane*8+0], vv1 = v_s[lane*8+1], \
                vv2 = v_s[lane*8+2], vv3 = v_s[lane*8+3], \
                vv4 = v_s[lane*8+4], vv5 = v_s[lane*8+5], \
                vv6 = v_s[lane*8+6], vv7 = v_s[lane*8+7]

#define SK_ACCUM(ui) \
    a0 = fmaf((ui), k0, a0); a1 = fmaf((ui), k1, a1); a2 = fmaf((ui), k2, a2); a3 = fmaf((ui), k3, a3); \
    a4 = fmaf((ui), k4, a4); a5 = fmaf((ui), k5, a5); a6 = fmaf((ui), k6, a6); a7 = fmaf((ui), k7, a7)

__launch_bounds__(1024)
__global__ void k_sinkhorn(const unsigned short* __restrict__ Kg,
                           float* __restrict__ lu, float* __restrict__ lv) {
    const int b = blockIdx.x;
    const uint4* __restrict__ Kb = (const uint4*)(Kg + (size_t)b * SK_N * SK_N);
    __shared__ uint4 Kl[SK_LR * 64];      // 114688 B: rows [0,112) of this batch's K
    __shared__ float part[16][SK_N];      //  32768 B: per-wave column partials
    __shared__ float v_s[SK_N];           //   2048 B
    const int tid  = threadIdx.x;
    const int lane = tid & 63;
    const int w    = tid >> 6;

    // ---- sweep 0: column sums with uniform u0 = 1/N; stash rows < SK_LR in LDS.
    // Rows i ≡ w (mod 16) are read back only by wave w -> no cross-wave hazard.
    {
        float a0=0.f,a1=0.f,a2=0.f,a3=0.f,a4=0.f,a5=0.f,a6=0.f,a7=0.f;
        for (int i = w; i < SK_N; i += 16) {
            uint4 p = Kb[i * 64 + lane];
            if (i < SK_LR) Kl[i * 64 + lane] = p;
            SK_UNPACK(p);
            a0 += k0; a1 += k1; a2 += k2; a3 += k3;
            a4 += k4; a5 += k5; a6 += k6; a7 += k7;
        }
        float* pr = &part[w][lane * 8];
        pr[0]=a0; pr[1]=a1; pr[2]=a2; pr[3]=a3; pr[4]=a4; pr[5]=a5; pr[6]=a6; pr[7]=a7;
        __syncthreads();
        if (tid < SK_N) {
            float s = 0.f;
            #pragma unroll
            for (int g = 0; g < 16; ++g) s += part[g][tid];
            v_s[tid] = __builtin_amdgcn_rcpf(s * (1.0f / SK_N));   // v1 = 1/((1/N)*sumK)
        }
        __syncthreads();
    }

    // ---- fused sweeps t = 1..49: per row i, u_i = 1/(K_i . v_t), then
    //      colsum_j += u_i * K_ij (produces v_{t+1}). One K read per iteration.
    for (int t = 1; t < SK_NIT; ++t) {
        SK_LOADVV();
        float a0=0.f,a1=0.f,a2=0.f,a3=0.f,a4=0.f,a5=0.f,a6=0.f,a7=0.f;
        // LDS-resident rows
        for (int i = w; i < SK_LR; i += 16) {
            uint4 p = Kl[i * 64 + lane];
            SK_UNPACK(p);
            SK_DOT_RED(s);
            const float ui = __builtin_amdgcn_rcpf(s);
            SK_ACCUM(ui);
        }
        // streamed rows, prefetched one ahead
        uint4 pg = Kb[(SK_LR + w) * 64 + lane];
        for (int i = SK_LR + w; i < SK_N; i += 16) {
            const uint4 p = pg;
            if (i + 16 < SK_N) pg = Kb[(i + 16) * 64 + lane];
            SK_UNPACK(p);
            SK_DOT_RED(s);
            const float ui = __builtin_amdgcn_rcpf(s);
            SK_ACCUM(ui);
        }
        float* pr = &part[w][lane * 8];
        pr[0]=a0; pr[1]=a1; pr[2]=a2; pr[3]=a3; pr[4]=a4; pr[5]=a5; pr[6]=a6; pr[7]=a7;
        __syncthreads();
        if (tid < SK_N) {
            float s = 0.f;
            #pragma unroll
            for (int g = 0; g < 16; ++g) s += part[g][tid];
            v_s[tid] = __builtin_amdgcn_rcpf(s);
        }
        __syncthreads();
    }

    // ---- final half-sweep: u50 = 1/(K v50); write log u, log v.
    {
        SK_LOADVV();
        for (int i = w; i < SK_LR; i += 16) {
            uint4 p = Kl[i * 64 + lane];
            SK_UNPACK(p);
            SK_DOT_RED(s);
            if (lane == 0) lu[b * SK_N + i] = -__logf(s);   // log u = -log(rowsum)
        }
        for (int i = SK_LR + w; i < SK_N; i += 16) {
            uint4 p = Kb[i * 64 + lane];
            SK_UNPACK(p);
            SK_DOT_RED(s);
            if (lane == 0) lu[b * SK_N + i] = -__logf(s);
        }
        if (tid < SK_N) lv[b * SK_N + tid] = __logf(v_s[tid]);
    }
}

__global__ void k_out(const float4* __restrict__ cost, const float* __restrict__ lu,
                      const float4* __restrict__ lv4, float4* __restrict__ out, int n4) {
    int idx = blockIdx.x * blockDim.x + threadIdx.x;
    if (idx >= n4) return;
    int bb  = idx >> 16;            // element e = idx*4; b = e>>18
    int row = (idx >> 7) & (SK_N - 1);
    int j4  = idx & 127;
    float  l_u = lu[bb * SK_N + row];
    float4 lvv = lv4[bb * 128 + j4];
    float4 c   = cost[idx];
    float4 o;
    o.x = l_u - c.x + lvv.x;
    o.y = l_u - c.y + lvv.y;
    o.z = l_u - c.z + lvv.z;
    o.w = l_u - c.w + lvv.w;
    out[idx] = o;
}

extern "C" void kernel_launch(void* const* d_in, const int* in_sizes, int n_in,
                              void* d_out, int out_size, void* d_ws, size_t ws_size,
                              hipStream_t stream) {
    const float* cost = (const float*)d_in[0];
    float* out = (float*)d_out;

    // bf16 K lives in the first half of d_out (128 MB of 256 MB); epilogue
    // reads only cost/lu/lv, so overwriting d_out at the end is safe.
    unsigned short* K = (unsigned short*)d_out;
    float* lu = (float*)d_ws;                 // 256*512 floats = 512 KB
    float* lv = lu + SK_B * SK_N;             // 512 KB

    const int n4 = SK_B * SK_N * SK_N / 4;    // 16,777,216 float4 groups

    k_makeK<<<8192, 256, 0, stream>>>((const float4*)cost, (ushort4*)K, n4);
    k_sinkhorn<<<SK_B, 1024, 0, stream>>>(K, lu, lv);
    k_out<<<n4 / 256, 256, 0, stream>>>((const float4*)cost, lu,
                                        (const float4*)lv, (float4*)out, n4);
}